// Round 14
// baseline (118.232 us; speedup 1.0000x reference)
//
#include <hip/hip_runtime.h>

// ---------------------------------------------------------------------------
// Attention block, MI355X bf16-MFMA implementation.  R14 (= R13 + new attn):
//  - attn: wave-independent, barrier-free flash.  Block = 32 q-rows, 4 waves;
//    wave w owns 32-key tiles t%4==w with PRIVATE 13KB LDS (K image 8KB +
//    V image 5KB), staged via fully-linear gload_lds from pre-tiled images.
//    Zero masks (tiles always in-segment), zero loop barriers; 3 blocks/CU =
//    12 independent waves/CU.  4-way online-softmax merge at end.
//  - gemm256 epilogue: K/V written as pre-swizzled tile images.
//  - gemm256 main loop / pack(A,B,wp) / proj: byte-identical to R13.
// ---------------------------------------------------------------------------

typedef __bf16 bf16;
typedef __bf16 bf16x4 __attribute__((ext_vector_type(4)));
typedef __bf16 bf16x8 __attribute__((ext_vector_type(8)));
typedef float f32x4 __attribute__((ext_vector_type(4)));
typedef float f32x16 __attribute__((ext_vector_type(16)));
typedef unsigned int u32;

constexpr int S = 3072;
constexpr int DIM = 1280;
constexpr int H = 16;
constexpr int HD = 80;
constexpr int NQKV = 3 * DIM;   // 3840
constexpr int NT32 = S / 32;    // 96 key tiles per head

constexpr int BM = 192;
constexpr int MB_A = S / BM;     // 16 panels
constexpr int NB_B = NQKV / 256; // 15
constexpr int NKT = DIM / 32;    // 40
constexpr int ASL = BM * 32 * 2;     // 12288 B per A slice
constexpr int SLOT = ASL + 16384;    // 28672 B per ring slot

constexpr int KIMG = 32 * 256;   // 8192 B per K tile image
constexpr int VIMG = 40 * 128;   // 5120 B per V tile image

// log2(e) / sqrt(80): folded into Q so scores are in exp2 domain.
constexpr float QSCALE = 1.4426950408889634f / 8.94427190999916f;

__device__ __forceinline__ void gload_lds16(const void* g, void* l) {
  __builtin_amdgcn_global_load_lds(
      (const __attribute__((address_space(1))) void*)g,
      (__attribute__((address_space(3))) void*)l, 16, 0, 0);
}

__device__ __forceinline__ u32 pkbf2(float a, float b) {
  union { bf16 h[2]; u32 w; } u;
  u.h[0] = (bf16)a; u.h[1] = (bf16)b;
  return u.w;
}

__device__ __forceinline__ int swv(int s) {
  return ((((s >> 3) & 31) ^ ((s & 7) << 2)) << 2);
}

// --------------------------- input packing ----------------------------------
constexpr long PA_CHUNKS = (long)MB_A * NKT * (ASL / 16);  // 491520
constexpr long PB_CHUNKS = (long)NB_B * NKT * 1024;        // 614400
constexpr long PW_CHUNKS = (long)DIM * DIM / 8;            // 204800
constexpr long KP_CHUNKS = (long)H * S * 48 / 8;           // 294912
constexpr long CS_CHUNKS = (long)S * 40 / 8;               // 15360
constexpr long TOT_CHUNKS = PA_CHUNKS + PB_CHUNKS + PW_CHUNKS + KP_CHUNKS + CS_CHUNKS;

__global__ __launch_bounds__(256) void pack_inputs(
    const float* __restrict__ x, const float* __restrict__ wq,
    const float* __restrict__ wp, const float* __restrict__ rope,
    bf16* __restrict__ pA, bf16* __restrict__ pB, bf16* __restrict__ wp16,
    bf16* __restrict__ Kb, float* __restrict__ ctab, float* __restrict__ stab) {
  long t = (long)blockIdx.x * 256 + threadIdx.x;
  if (t < PA_CHUNKS) {
    const int blk = (int)(t / (NKT * 768)), rem = (int)(t % (NKT * 768));
    const int kt = rem / 768, c = rem - kt * 768;
    const int lin = c * 16;
    const int logi = lin ^ (((lin >> 7) & 7) << 4);
    const int row = logi >> 6, col = (logi & 63) >> 1;
    const float* src = x + (size_t)(blk * BM + row) * DIM + kt * 32 + col;
    float4 v0 = *(const float4*)src;
    float4 v1 = *(const float4*)(src + 4);
    bf16x8 o = {(bf16)v0.x, (bf16)v0.y, (bf16)v0.z, (bf16)v0.w,
                (bf16)v1.x, (bf16)v1.y, (bf16)v1.z, (bf16)v1.w};
    *(bf16x8*)(pA + t * 8) = o;
  } else if (t < PA_CHUNKS + PB_CHUNKS) {
    long t2 = t - PA_CHUNKS;
    const int blk = (int)(t2 / (NKT * 1024)), rem = (int)(t2 % (NKT * 1024));
    const int kt = rem >> 10, c = rem & 1023;
    const int lin = c * 16;
    const int logi = lin ^ (((lin >> 7) & 7) << 4);
    const int row = logi >> 6, col = (logi & 63) >> 1;
    int grow = blk * 256 + row;
    if (grow < 2560) {  // permute q/k rows: pairs adjacent
      const int ty = grow / 1280, rm = grow % 1280;
      const int h = rm / 80, p = rm % 80;
      grow = ty * 1280 + h * 80 + (p >> 1) + (p & 1) * 40;
    }
    const float* src = wq + (size_t)grow * DIM + kt * 32 + col;
    float4 v0 = *(const float4*)src;
    float4 v1 = *(const float4*)(src + 4);
    bf16x8 o = {(bf16)v0.x, (bf16)v0.y, (bf16)v0.z, (bf16)v0.w,
                (bf16)v1.x, (bf16)v1.y, (bf16)v1.z, (bf16)v1.w};
    *(bf16x8*)(pB + t2 * 8) = o;
  } else if (t < PA_CHUNKS + PB_CHUNKS + PW_CHUNKS) {
    long t2 = t - PA_CHUNKS - PB_CHUNKS;
    const float* src = wp + t2 * 8;
    float4 v0 = *(const float4*)src;
    float4 v1 = *(const float4*)(src + 4);
    bf16x8 o = {(bf16)v0.x, (bf16)v0.y, (bf16)v0.z, (bf16)v0.w,
                (bf16)v1.x, (bf16)v1.y, (bf16)v1.z, (bf16)v1.w};
    *(bf16x8*)(wp16 + t2 * 8) = o;
  } else if (t < PA_CHUNKS + PB_CHUNKS + PW_CHUNKS + KP_CHUNKS) {
    // zero K pad cols [80,128) in the tiled K images
    long t2 = t - PA_CHUNKS - PB_CHUNKS - PW_CHUNKS;
    const int h = (int)(t2 / (S * 6)), r0 = (int)(t2 % (S * 6));
    const int s = r0 / 6, cc = r0 % 6;
    const int tile = s >> 5, r = s & 31;
    const int p = 80 + cc * 8;
    bf16x8 z = {};
    *(bf16x8*)((char*)Kb + (size_t)(h * NT32 + tile) * KIMG + r * 256 +
               ((2 * p) ^ ((r & 15) << 4))) = z;
  } else {
    long t3 = t - PA_CHUNKS - PB_CHUNKS - PW_CHUNKS - KP_CHUNKS;
#pragma unroll
    for (int k = 0; k < 8; k++) {
      const int idx = (int)(t3 * 8 + k);
      const int s = idx / 40, a = idx % 40;
      float sn, cs;
      __sincosf(rope[idx], &sn, &cs);
      ctab[a * S + s] = cs;
      stab[a * S + s] = sn;
    }
  }
}

// --------------------------- fused QKV GEMM + rope/scatter ------------------
// 192x256 tile, 8 waves, 4-slot ring, grid 240.  Epilogue writes Q rows,
// K tile images [32][256B] (swz (r&15)<<4), V tile images [40][128B]
// (paired dims, swz (j&7)<<4).
__global__ __launch_bounds__(512, 2) void gemm256(
    const bf16* __restrict__ pA, const bf16* __restrict__ pB,
    const float* __restrict__ bias, const float* __restrict__ ctab,
    const float* __restrict__ stab, bf16* __restrict__ Qb,
    bf16* __restrict__ Kb, bf16* __restrict__ VTb) {
  extern __shared__ char lds[];
  const int tid = threadIdx.x;
  const int w = tid >> 6, lane = tid & 63;
  const int r15 = lane & 15, b4 = lane >> 4;
  const int wr = w >> 2, wc = w & 3;
  const int nwg = gridDim.x * gridDim.y;  // 240
  const int orig = blockIdx.y * gridDim.x + blockIdx.x;
  const int xcd = orig % 8, loc = orig / 8;
  const int qq = nwg / 8, rq = nwg % 8;
  const int swzid =
      (xcd < rq ? xcd * (qq + 1) : rq * (qq + 1) + (xcd - rq) * qq) + loc;
  const int nb = swzid % gridDim.x, mb = swzid / gridDim.x;
  const int m0 = mb * BM;
  const char* aPanel = (const char*)pA + (size_t)mb * NKT * ASL;
  const char* bPanel = (const char*)pB + (size_t)nb * NKT * 16384;
  auto stageA = [&](int kt) {
    char* s = lds + (kt & 3) * SLOT;
    const char* g = aPanel + (size_t)kt * ASL;
    gload_lds16(g + tid * 16, s + tid * 16);
    if (tid < 256)
      gload_lds16(g + 8192 + tid * 16, s + 8192 + tid * 16);
  };
  auto stageB = [&](int kt) {
    char* s = lds + (kt & 3) * SLOT + ASL;
    const char* g = bPanel + (size_t)kt * 16384;
    gload_lds16(g + tid * 16, s + tid * 16);
    gload_lds16(g + 8192 + tid * 16, s + 8192 + tid * 16);
  };
  f32x4 acc[6][4] = {};
  stageA(0); stageB(0); stageA(1); stageB(1); stageA(2); stageB(2);
  if (tid < 256) asm volatile("s_waitcnt vmcnt(8)" ::: "memory");
  else           asm volatile("s_waitcnt vmcnt(6)" ::: "memory");
  __builtin_amdgcn_s_barrier();
  for (int kt = 0; kt < NKT; ++kt) {
    const char* As = lds + (kt & 3) * SLOT;
    const char* Bs = As + ASL;
    const bool pf = (kt + 3 < NKT);
    bf16x8 afr[3], bfr[4];
#pragma unroll
    for (int i = 0; i < 3; i++) {
      int a = (wr * 96 + i * 16 + r15) * 64 + b4 * 16;
      a ^= ((a >> 7) & 7) << 4;
      afr[i] = *(const bf16x8*)(As + a);
    }
#pragma unroll
    for (int j = 0; j < 4; j++) {
      int a = (wc * 64 + j * 16 + r15) * 64 + b4 * 16;
      a ^= ((a >> 7) & 7) << 4;
      bfr[j] = *(const bf16x8*)(Bs + a);
    }
    if (pf) stageA(kt + 3);
    asm volatile("" ::: "memory");
    __builtin_amdgcn_s_barrier();
    __builtin_amdgcn_s_setprio(1);
#pragma unroll
    for (int i = 0; i < 3; i++)
#pragma unroll
      for (int j = 0; j < 4; j++)
        acc[i][j] = __builtin_amdgcn_mfma_f32_16x16x32_bf16(afr[i], bfr[j],
                                                            acc[i][j], 0, 0, 0);
    __builtin_amdgcn_s_setprio(0);
    asm volatile("" ::: "memory");
    __builtin_amdgcn_s_barrier();
#pragma unroll
    for (int i = 0; i < 3; i++) {
      int a = (wr * 96 + 48 + i * 16 + r15) * 64 + b4 * 16;
      a ^= ((a >> 7) & 7) << 4;
      afr[i] = *(const bf16x8*)(As + a);
    }
    if (pf) stageB(kt + 3);
    asm volatile("" ::: "memory");
    __builtin_amdgcn_s_barrier();
    __builtin_amdgcn_s_setprio(1);
#pragma unroll
    for (int i = 0; i < 3; i++)
#pragma unroll
      for (int j = 0; j < 4; j++)
        acc[3 + i][j] = __builtin_amdgcn_mfma_f32_16x16x32_bf16(
            afr[i], bfr[j], acc[3 + i][j], 0, 0, 0);
    __builtin_amdgcn_s_setprio(0);
    const int rem = NKT - 2 - kt;
    if (tid < 256) {
      if (rem >= 2)      asm volatile("s_waitcnt vmcnt(8)" ::: "memory");
      else if (rem == 1) asm volatile("s_waitcnt vmcnt(4)" ::: "memory");
      else if (rem == 0) asm volatile("s_waitcnt vmcnt(0)" ::: "memory");
      else               asm volatile("" ::: "memory");
    } else {
      if (rem >= 2)      asm volatile("s_waitcnt vmcnt(6)" ::: "memory");
      else if (rem == 1) asm volatile("s_waitcnt vmcnt(3)" ::: "memory");
      else if (rem == 0) asm volatile("s_waitcnt vmcnt(0)" ::: "memory");
      else               asm volatile("" ::: "memory");
    }
    __builtin_amdgcn_s_barrier();
  }
  // ------------------- fused epilogue (192 rows) -------------------
  const int n0 = nb * 256;
  const int type = n0 / 1280;            // 0=Q 1=K 2=V
  const int cpart0 = n0 - type * 1280;
  if (type < 2) {
#pragma unroll
    for (int j = 0; j < 4; j++) {
      const int c = wc * 64 + j * 16 + r15;
      const int cp = cpart0 + c;
      const int h = cp / 80, p = cp % 80;
      const int d = (p >> 1) + (p & 1) * 40;
      const float bv = bias[type * 1280 + h * 80 + d];
      const int a = p >> 1;
#pragma unroll
      for (int i = 0; i < 6; i++) {
        const int sl = wr * 96 + i * 16 + b4 * 4;
        f32x4 cs4 = *(const f32x4*)&ctab[a * S + m0 + sl];
        f32x4 sn4 = *(const f32x4*)&stab[a * S + m0 + sl];
#pragma unroll
        for (int r = 0; r < 4; r++) {
          float v = acc[i][j][r] + bv;
          float ov = __shfl_xor(v, 1);
          float res = (p & 1) ? (v * cs4[r] + ov * sn4[r])
                              : (v * cs4[r] - ov * sn4[r]);
          if (type == 0) res *= QSCALE;
          *(bf16*)(lds + (sl + r) * 512 + ((2 * c) ^ (((sl + r) & 7) << 4))) =
              (bf16)res;
        }
      }
    }
    __syncthreads();
#pragma unroll
    for (int t = 0; t < 12; t++) {
      const int task = t * 512 + tid;
      const int sl = task >> 5, c = (task & 31) * 8;
      bf16x8 v = *(const bf16x8*)(lds + sl * 512 + ((2 * c) ^ ((sl & 7) << 4)));
      const int cp = cpart0 + c, h = cp / 80, p = cp % 80;
      if (type == 0) {
        *(bf16x8*)(Qb + ((size_t)h * S + m0 + sl) * HD + p) = v;
      } else {
        const int s = m0 + sl, tile = s >> 5, r = s & 31;
        *(bf16x8*)((char*)Kb + (size_t)(h * NT32 + tile) * KIMG + r * 256 +
                   ((2 * p) ^ ((r & 15) << 4))) = v;
      }
    }
  } else {
#pragma unroll
    for (int j = 0; j < 4; j++) {
      const int c = wc * 64 + j * 16 + r15;
      const float bv = bias[2560 + cpart0 + c];
#pragma unroll
      for (int i = 0; i < 6; i++) {
        const int sl = wr * 96 + i * 16 + b4 * 4;
#pragma unroll
        for (int r = 0; r < 4; r++) {
          *(bf16*)(lds + (sl + r) * 512 + ((2 * c) ^ swv(sl + r))) =
              (bf16)(acc[i][j][r] + bv);
        }
      }
    }
    __syncthreads();
#pragma unroll
    for (int t = 0; t < 12; t++) {
      const int task = t * 512 + tid;
      const int c = task & 255, s0 = (task >> 8) * 8;
      union { bf16 h[8]; bf16x8 v; } o;
#pragma unroll
      for (int e = 0; e < 8; e++)
        o.h[e] = *(const bf16*)(lds + (s0 + e) * 512 + ((2 * c) ^ swv(s0 + e)));
      const int cp = cpart0 + c, h = cp / 80, d = cp % 80;
      const int s0g = m0 + s0, tile = s0g >> 5, sin = s0g & 31;
      const int jrow = d >> 1;
      *(bf16x8*)((char*)VTb + (size_t)(h * NT32 + tile) * VIMG + jrow * 128 +
                 (((d & 1) * 64 + sin * 2) ^ ((jrow & 7) << 4))) = o.v;
    }
  }
}

// --------------------------- proj GEMM (unchanged) --------------------------
__global__ __launch_bounds__(256) void gemm_proj(
    const bf16* __restrict__ A, const bf16* __restrict__ B,
    const float* __restrict__ bias, float* __restrict__ Cout, int M, int N,
    int K) {
  __shared__ bf16 Al[2][64 * 32];
  __shared__ bf16 Bl[2][128 * 32];
  const int tid = threadIdx.x;
  const int w = tid >> 6, lane = tid & 63;
  const int r15 = lane & 15, b4 = lane >> 4;
  const int nwg = gridDim.x * gridDim.y;
  const int orig = blockIdx.y * gridDim.x + blockIdx.x;
  const int swzid = (orig & 7) * (nwg >> 3) + (orig >> 3);
  const int bx = swzid % gridDim.x, by = swzid / gridDim.x;
  const int m0 = by * 64, n0 = bx * 128;
  const int wm = (w >> 1) * 32, wn = (w & 1) * 64;
  f32x4 acc[2][4] = {};
  const int row0 = tid >> 2, ko0 = (tid & 3) * 8;
  const bf16* Ar = A + (size_t)(m0 + row0) * K + ko0;
  const bf16* Br0 = B + (size_t)(n0 + row0) * K + ko0;
  const bf16* Br1 = B + (size_t)(n0 + row0 + 64) * K + ko0;

  auto stage = [&](int buf, int k0) {
    gload_lds16(Ar + k0, (char*)Al[buf] + tid * 16);
    gload_lds16(Br0 + k0, (char*)Bl[buf] + tid * 16);
    gload_lds16(Br1 + k0, (char*)Bl[buf] + 4096 + tid * 16);
  };

  stage(0, 0);
  int cur = 0;
  for (int k0 = 0; k0 < K; k0 += 32) {
    __syncthreads();
    if (k0 + 32 < K) stage(cur ^ 1, k0 + 32);
    bf16x8 af[2], bfr[4];
#pragma unroll
    for (int i = 0; i < 2; i++)
      af[i] = *(const bf16x8*)((const char*)Al[cur] + (wm + i * 16 + r15) * 64 + b4 * 16);
#pragma unroll
    for (int j = 0; j < 4; j++)
      bfr[j] = *(const bf16x8*)((const char*)Bl[cur] + (wn + j * 16 + r15) * 64 + b4 * 16);
#pragma unroll
    for (int i = 0; i < 2; i++)
#pragma unroll
      for (int j = 0; j < 4; j++)
        acc[i][j] = __builtin_amdgcn_mfma_f32_16x16x32_bf16(af[i], bfr[j], acc[i][j], 0, 0, 0);
    cur ^= 1;
  }
#pragma unroll
  for (int j = 0; j < 4; j++) {
    const int n = n0 + wn + j * 16 + r15;
    const float bv = bias[n];
#pragma unroll
    for (int i = 0; i < 2; i++) {
      const int mr = m0 + wm + i * 16 + b4 * 4;
#pragma unroll
      for (int r = 0; r < 4; r++)
        Cout[(size_t)(mr + r) * N + n] = acc[i][j][r] + bv;
    }
  }
}

// --------------------------- flash attention (wave-independent) -------------
// Block = 32 q-rows of one head, 4 waves.  Wave w owns 32-key tiles t%4==w
// with private 13KB LDS; fully-linear staging from tile images; no masks, no
// loop barriers.  4-way merge at end.
__global__ __launch_bounds__(256, 3) void attn_kern(
    const bf16* __restrict__ Qg, const bf16* __restrict__ Kt,
    const bf16* __restrict__ Vt, const int* __restrict__ cu, int nseg,
    bf16* __restrict__ Out) {
  __shared__ char SL[4][KIMG + VIMG];  // 53248 B
  const int tid = threadIdx.x, w = tid >> 6, lane = tid & 63;
  const int r31 = lane & 31, hi = lane >> 5;
  const int nwg = gridDim.x;  // 1536
  const int orig = blockIdx.x;
  const int swzb = (orig & 7) * (nwg >> 3) + (orig >> 3);
  const int h = swzb / 96, qb = swzb % 96;
  const int q = qb * 32 + r31;
  int lo = 0, hik = S;
  {
    const int qlo = qb * 32;
#pragma unroll
    for (int i = 0; i < 8; i++) {
      if (i >= nseg) break;
      int a = cu[i], b = cu[i + 1];
      if (qlo >= a && qlo < b) { lo = a; hik = b; }
    }
  }
  bf16x8 qf[5];
  {
    const bf16* qrow = Qg + ((size_t)h * S + q) * HD + hi * 8;
#pragma unroll
    for (int kk = 0; kk < 5; kk++) qf[kk] = *(const bf16x8*)(qrow + kk * 16);
  }
  char* myK = SL[w];
  char* myV = SL[w] + KIMG;
  const char* Kh = (const char*)Kt + (size_t)h * NT32 * KIMG;
  const char* Vh = (const char*)Vt + (size_t)h * NT32 * VIMG;
  f32x16 o0 = {}, o1 = {}, o2 = {};
  float m = -1e30f, l = 0.f;
  const int nt = (hik - lo) >> 5;
  const int t0 = lo >> 5;
  for (int t = w; t < nt; t += 4) {
    const char* gK = Kh + (size_t)(t0 + t) * KIMG;
    const char* gV = Vh + (size_t)(t0 + t) * VIMG;
#pragma unroll
    for (int c = 0; c < 8; c++)
      gload_lds16(gK + (c * 64 + lane) * 16, myK + (c * 64 + lane) * 16);
#pragma unroll
    for (int c = 0; c < 5; c++)
      gload_lds16(gV + (c * 64 + lane) * 16, myV + (c * 64 + lane) * 16);
    asm volatile("s_waitcnt vmcnt(0)" ::: "memory");
    // ---- S^T = K * Q^T (32 keys) ----
    f32x16 st0 = {};
#pragma unroll
    for (int kk = 0; kk < 5; kk++) {
      bf16x8 kf = *(const bf16x8*)(myK + r31 * 256 +
                                   ((kk * 32 + hi * 16) ^ ((r31 & 15) << 4)));
      st0 = __builtin_amdgcn_mfma_f32_32x32x16_bf16(kf, qf[kk], st0, 0, 0, 0);
    }
    // ---- online softmax (no mask: tile always in-segment) ----
    float tm = -3e38f;
#pragma unroll
    for (int j = 0; j < 16; j++) tm = fmaxf(tm, st0[j]);
    tm = fmaxf(tm, __shfl_xor(tm, 32));
    if (!__all(tm <= m + 8.f)) {  // defer-max
      const float mn = fmaxf(m, tm);
      const float alpha = __builtin_amdgcn_exp2f(m - mn);
      o0 *= alpha; o1 *= alpha; o2 *= alpha;
      l *= alpha;
      m = mn;
    }
    float rs = 0.f;
    u32 wd0[4][2];
#pragma unroll
    for (int g2 = 0; g2 < 4; g2++) {
#pragma unroll
      for (int hh = 0; hh < 2; hh++) {
        float a0 = __builtin_amdgcn_exp2f(st0[g2 * 4 + 2 * hh] - m);
        float a1 = __builtin_amdgcn_exp2f(st0[g2 * 4 + 2 * hh + 1] - m);
        rs += a0 + a1;
        wd0[g2][hh] = pkbf2(a0, a1);
      }
    }
    rs += __shfl_xor(rs, 32);
    l += rs;
    // ---- O^T += V^T * P^T ----
#pragma unroll
    for (int kk = 0; kk < 2; kk++) {
      const int g2o = kk * 2 + hi;
      const int g2s = kk * 2 + (hi ^ 1);
      u32 own0 = wd0[g2o][0], own1 = wd0[g2o][1];
      u32 snd0 = wd0[g2s][0], snd1 = wd0[g2s][1];
      u32 rc0 = (u32)__shfl_xor((int)snd0, 32);
      u32 rc1 = (u32)__shfl_xor((int)snd1, 32);
      union { u32 w[4]; bf16x8 v; } pf;
      if (hi == 0) { pf.w[0] = own0; pf.w[1] = own1; pf.w[2] = rc0; pf.w[3] = rc1; }
      else         { pf.w[0] = rc0;  pf.w[1] = rc1;  pf.w[2] = own0; pf.w[3] = own1; }
#pragma unroll
      for (int mt = 0; mt < 3; mt++) {
        int d = mt * 32 + r31;
        d = d < HD ? d : 0;  // pad rows: garbage isolated to unstored C rows
        const int jrow = d >> 1;
        bf16x8 vf = *(const bf16x8*)(myV + jrow * 128 +
                                     (((d & 1) * 64 + kk * 32 + hi * 16) ^
                                      ((jrow & 7) << 4)));
        f32x16* op = mt == 0 ? &o0 : (mt == 1 ? &o1 : &o2);
        *op = __builtin_amdgcn_mfma_f32_32x32x16_bf16(vf, pf.v, *op, 0, 0, 0);
      }
    }
  }
  // ---- 4-way merge: waves 1-3 publish, wave 0 merges + stores ----
  __syncthreads();
  float* mb = (float*)SL;  // 3 x 64 x 50 floats = 38400 B
  if (w) {
    float* d = mb + ((size_t)(w - 1) * 64 + lane) * 50;
    d[0] = m; d[1] = l;
#pragma unroll
    for (int j = 0; j < 16; j++) { d[2 + j] = o0[j]; d[18 + j] = o1[j]; d[34 + j] = o2[j]; }
  }
  __syncthreads();
  if (w == 0) {
#pragma unroll
    for (int s = 0; s < 3; s++) {
      const float* d = mb + ((size_t)s * 64 + lane) * 50;
      const float pm = d[0], pl = d[1];
      const float mn = fmaxf(m, pm);
      const float a = __builtin_amdgcn_exp2f(m - mn);
      const float b = __builtin_amdgcn_exp2f(pm - mn);
#pragma unroll
      for (int j = 0; j < 16; j++) {
        o0[j] = o0[j] * a + d[2 + j] * b;
        o1[j] = o1[j] * a + d[18 + j] * b;
        o2[j] = o2[j] * a + d[34 + j] * b;
      }
      l = l * a + pl * b;
      m = mn;
    }
    const float inv = 1.f / l;
    bf16* orow = Out + (size_t)q * DIM + h * HD;
#pragma unroll
    for (int rg = 0; rg < 4; rg++) {
      bf16x4 v0 = {(bf16)(o0[rg * 4] * inv), (bf16)(o0[rg * 4 + 1] * inv),
                   (bf16)(o0[rg * 4 + 2] * inv), (bf16)(o0[rg * 4 + 3] * inv)};
      *(bf16x4*)(orow + 8 * rg + 4 * hi) = v0;
      bf16x4 v1 = {(bf16)(o1[rg * 4] * inv), (bf16)(o1[rg * 4 + 1] * inv),
                   (bf16)(o1[rg * 4 + 2] * inv), (bf16)(o1[rg * 4 + 3] * inv)};
      *(bf16x4*)(orow + 32 + 8 * rg + 4 * hi) = v1;
    }
#pragma unroll
    for (int rg = 0; rg < 2; rg++) {
      bf16x4 v2 = {(bf16)(o2[rg * 4] * inv), (bf16)(o2[rg * 4 + 1] * inv),
                   (bf16)(o2[rg * 4 + 2] * inv), (bf16)(o2[rg * 4 + 3] * inv)};
      *(bf16x4*)(orow + 64 + 8 * rg + 4 * hi) = v2;
    }
  }
}

// --------------------------- launch -----------------------------------------
extern "C" void kernel_launch(void* const* d_in, const int* in_sizes, int n_in,
                              void* d_out, int out_size, void* d_ws,
                              size_t ws_size, hipStream_t stream) {
  const float* x = (const float*)d_in[0];
  const int* cu = (const int*)d_in[1];
  const float* rope = (const float*)d_in[2];
  const float* w_qkv = (const float*)d_in[3];
  const float* b_qkv = (const float*)d_in[4];
  const float* w_proj = (const float*)d_in[5];
  const float* b_proj = (const float*)d_in[6];
  const int nseg = in_sizes[1] - 1;

  bf16* pA = (bf16*)d_ws;                          // dead after gemm256
  bf16* pB = pA + (size_t)S * DIM;
  bf16* wp16 = pB + (size_t)NQKV * DIM;
  bf16* Qb = wp16 + (size_t)DIM * DIM;             // H*S*80
  bf16* Kb = Qb + (size_t)H * S * HD;              // K tile images (H*S*128)
  bf16* VTb = Kb + (size_t)H * S * 128;            // V tile images (H*S*80)
  float* ctab = (float*)(VTb + (size_t)H * HD * S);
  float* stab = ctab + (size_t)S * 40;
  bf16* attn16 = pA;                               // alias dead pA

  pack_inputs<<<(int)(TOT_CHUNKS / 256), 256, 0, stream>>>(
      x, w_qkv, w_proj, rope, pA, pB, wp16, Kb, ctab, stab);
  gemm256<<<dim3(NB_B, MB_A), 512, 114688, stream>>>(
      pA, pB, b_qkv, ctab, stab, Qb, Kb, VTb);
  attn_kern<<<H * 96, 256, 0, stream>>>(Qb, Kb, VTb, cu, nseg, attn16);
  gemm_proj<<<dim3(DIM / 128, S / 64), 256, 0, stream>>>(
      attn16, wp16, b_proj, (float*)d_out, S, DIM, DIM);
}

// Round 15
// 110.552 us; speedup vs baseline: 1.0695x; 1.0695x over previous
//
#include <hip/hip_runtime.h>

// ---------------------------------------------------------------------------
// Attention block, MI355X bf16-MFMA implementation.  R15 (= R13 + attn T4):
//  - attn (split-key, as R13) loop rebuilt with raw s_barrier + counted
//    vmcnt: stage K(8)+V(5) -> vmcnt(5) -> bar -> QK+softmax (V in flight)
//    -> vmcnt(0) -> bar -> PV.  __syncthreads' implicit full drain removed.
//  - gemm256 (192x256) / pack / proj: byte-identical to R13.
// ---------------------------------------------------------------------------

typedef __bf16 bf16;
typedef __bf16 bf16x4 __attribute__((ext_vector_type(4)));
typedef __bf16 bf16x8 __attribute__((ext_vector_type(8)));
typedef float f32x4 __attribute__((ext_vector_type(4)));
typedef float f32x16 __attribute__((ext_vector_type(16)));
typedef unsigned int u32;

constexpr int S = 3072;
constexpr int DIM = 1280;
constexpr int H = 16;
constexpr int HD = 80;
constexpr int KDP = 128;        // K head-dim padded (row stride)
constexpr int NQKV = 3 * DIM;   // 3840

constexpr int BM = 192;
constexpr int MB_A = S / BM;     // 16 panels
constexpr int NB_B = NQKV / 256; // 15
constexpr int NKT = DIM / 32;    // 40
constexpr int ASL = BM * 32 * 2;     // 12288 B per A slice
constexpr int SLOT = ASL + 16384;    // 28672 B per ring slot

// log2(e) / sqrt(80): folded into Q so scores are in exp2 domain.
constexpr float QSCALE = 1.4426950408889634f / 8.94427190999916f;

__device__ __forceinline__ void gload_lds16(const void* g, void* l) {
  __builtin_amdgcn_global_load_lds(
      (const __attribute__((address_space(1))) void*)g,
      (__attribute__((address_space(3))) void*)l, 16, 0, 0);
}

__device__ __forceinline__ u32 pkbf2(float a, float b) {
  union { bf16 h[2]; u32 w; } u;
  u.h[0] = (bf16)a; u.h[1] = (bf16)b;
  return u.w;
}

__device__ __forceinline__ int swv(int s) {
  return ((((s >> 3) & 31) ^ ((s & 7) << 2)) << 2);
}

// --------------------------- input packing (= R13) --------------------------
constexpr long PA_CHUNKS = (long)MB_A * NKT * (ASL / 16);  // 491520
constexpr long PB_CHUNKS = (long)NB_B * NKT * 1024;        // 614400
constexpr long PW_CHUNKS = (long)DIM * DIM / 8;            // 204800
constexpr long KP_CHUNKS = (long)H * S * 48 / 8;           // 294912
constexpr long CS_CHUNKS = (long)S * 40 / 8;               // 15360
constexpr long TOT_CHUNKS = PA_CHUNKS + PB_CHUNKS + PW_CHUNKS + KP_CHUNKS + CS_CHUNKS;

__global__ __launch_bounds__(256) void pack_inputs(
    const float* __restrict__ x, const float* __restrict__ wq,
    const float* __restrict__ wp, const float* __restrict__ rope,
    bf16* __restrict__ pA, bf16* __restrict__ pB, bf16* __restrict__ wp16,
    bf16* __restrict__ Kb, float* __restrict__ ctab, float* __restrict__ stab) {
  long t = (long)blockIdx.x * 256 + threadIdx.x;
  if (t < PA_CHUNKS) {
    const int blk = (int)(t / (NKT * 768)), rem = (int)(t % (NKT * 768));
    const int kt = rem / 768, c = rem - kt * 768;
    const int lin = c * 16;
    const int logi = lin ^ (((lin >> 7) & 7) << 4);
    const int row = logi >> 6, col = (logi & 63) >> 1;
    const float* src = x + (size_t)(blk * BM + row) * DIM + kt * 32 + col;
    float4 v0 = *(const float4*)src;
    float4 v1 = *(const float4*)(src + 4);
    bf16x8 o = {(bf16)v0.x, (bf16)v0.y, (bf16)v0.z, (bf16)v0.w,
                (bf16)v1.x, (bf16)v1.y, (bf16)v1.z, (bf16)v1.w};
    *(bf16x8*)(pA + t * 8) = o;
  } else if (t < PA_CHUNKS + PB_CHUNKS) {
    long t2 = t - PA_CHUNKS;
    const int blk = (int)(t2 / (NKT * 1024)), rem = (int)(t2 % (NKT * 1024));
    const int kt = rem >> 10, c = rem & 1023;
    const int lin = c * 16;
    const int logi = lin ^ (((lin >> 7) & 7) << 4);
    const int row = logi >> 6, col = (logi & 63) >> 1;
    int grow = blk * 256 + row;
    if (grow < 2560) {  // permute q/k rows: pairs adjacent
      const int ty = grow / 1280, rm = grow % 1280;
      const int h = rm / 80, p = rm % 80;
      grow = ty * 1280 + h * 80 + (p >> 1) + (p & 1) * 40;
    }
    const float* src = wq + (size_t)grow * DIM + kt * 32 + col;
    float4 v0 = *(const float4*)src;
    float4 v1 = *(const float4*)(src + 4);
    bf16x8 o = {(bf16)v0.x, (bf16)v0.y, (bf16)v0.z, (bf16)v0.w,
                (bf16)v1.x, (bf16)v1.y, (bf16)v1.z, (bf16)v1.w};
    *(bf16x8*)(pB + t2 * 8) = o;
  } else if (t < PA_CHUNKS + PB_CHUNKS + PW_CHUNKS) {
    long t2 = t - PA_CHUNKS - PB_CHUNKS;
    const float* src = wp + t2 * 8;
    float4 v0 = *(const float4*)src;
    float4 v1 = *(const float4*)(src + 4);
    bf16x8 o = {(bf16)v0.x, (bf16)v0.y, (bf16)v0.z, (bf16)v0.w,
                (bf16)v1.x, (bf16)v1.y, (bf16)v1.z, (bf16)v1.w};
    *(bf16x8*)(wp16 + t2 * 8) = o;
  } else if (t < PA_CHUNKS + PB_CHUNKS + PW_CHUNKS + KP_CHUNKS) {
    long t2 = t - PA_CHUNKS - PB_CHUNKS - PW_CHUNKS;
    const int h = (int)(t2 / (S * 6)), r = (int)(t2 % (S * 6));
    const int s = r / 6, cc = r % 6;
    bf16x8 z = {};
    *(bf16x8*)(Kb + ((size_t)h * S + s) * KDP + 80 + cc * 8) = z;
  } else {
    long t3 = t - PA_CHUNKS - PB_CHUNKS - PW_CHUNKS - KP_CHUNKS;
#pragma unroll
    for (int k = 0; k < 8; k++) {
      const int idx = (int)(t3 * 8 + k);
      const int s = idx / 40, a = idx % 40;
      float sn, cs;
      __sincosf(rope[idx], &sn, &cs);
      ctab[a * S + s] = cs;
      stab[a * S + s] = sn;
    }
  }
}

// --------------------------- fused QKV GEMM + rope/scatter (= R13) ----------
__global__ __launch_bounds__(512, 2) void gemm256(
    const bf16* __restrict__ pA, const bf16* __restrict__ pB,
    const float* __restrict__ bias, const float* __restrict__ ctab,
    const float* __restrict__ stab, bf16* __restrict__ Qb,
    bf16* __restrict__ Kb, bf16* __restrict__ VTb) {
  extern __shared__ char lds[];
  const int tid = threadIdx.x;
  const int w = tid >> 6, lane = tid & 63;
  const int r15 = lane & 15, b4 = lane >> 4;
  const int wr = w >> 2, wc = w & 3;
  const int nwg = gridDim.x * gridDim.y;  // 240
  const int orig = blockIdx.y * gridDim.x + blockIdx.x;
  const int xcd = orig % 8, loc = orig / 8;
  const int qq = nwg / 8, rq = nwg % 8;
  const int swzid =
      (xcd < rq ? xcd * (qq + 1) : rq * (qq + 1) + (xcd - rq) * qq) + loc;
  const int nb = swzid % gridDim.x, mb = swzid / gridDim.x;
  const int m0 = mb * BM;
  const char* aPanel = (const char*)pA + (size_t)mb * NKT * ASL;
  const char* bPanel = (const char*)pB + (size_t)nb * NKT * 16384;
  auto stageA = [&](int kt) {
    char* s = lds + (kt & 3) * SLOT;
    const char* g = aPanel + (size_t)kt * ASL;
    gload_lds16(g + tid * 16, s + tid * 16);
    if (tid < 256)
      gload_lds16(g + 8192 + tid * 16, s + 8192 + tid * 16);
  };
  auto stageB = [&](int kt) {
    char* s = lds + (kt & 3) * SLOT + ASL;
    const char* g = bPanel + (size_t)kt * 16384;
    gload_lds16(g + tid * 16, s + tid * 16);
    gload_lds16(g + 8192 + tid * 16, s + 8192 + tid * 16);
  };
  f32x4 acc[6][4] = {};
  stageA(0); stageB(0); stageA(1); stageB(1); stageA(2); stageB(2);
  if (tid < 256) asm volatile("s_waitcnt vmcnt(8)" ::: "memory");
  else           asm volatile("s_waitcnt vmcnt(6)" ::: "memory");
  __builtin_amdgcn_s_barrier();
  for (int kt = 0; kt < NKT; ++kt) {
    const char* As = lds + (kt & 3) * SLOT;
    const char* Bs = As + ASL;
    const bool pf = (kt + 3 < NKT);
    bf16x8 afr[3], bfr[4];
#pragma unroll
    for (int i = 0; i < 3; i++) {
      int a = (wr * 96 + i * 16 + r15) * 64 + b4 * 16;
      a ^= ((a >> 7) & 7) << 4;
      afr[i] = *(const bf16x8*)(As + a);
    }
#pragma unroll
    for (int j = 0; j < 4; j++) {
      int a = (wc * 64 + j * 16 + r15) * 64 + b4 * 16;
      a ^= ((a >> 7) & 7) << 4;
      bfr[j] = *(const bf16x8*)(Bs + a);
    }
    if (pf) stageA(kt + 3);
    asm volatile("" ::: "memory");
    __builtin_amdgcn_s_barrier();
    __builtin_amdgcn_s_setprio(1);
#pragma unroll
    for (int i = 0; i < 3; i++)
#pragma unroll
      for (int j = 0; j < 4; j++)
        acc[i][j] = __builtin_amdgcn_mfma_f32_16x16x32_bf16(afr[i], bfr[j],
                                                            acc[i][j], 0, 0, 0);
    __builtin_amdgcn_s_setprio(0);
    asm volatile("" ::: "memory");
    __builtin_amdgcn_s_barrier();
#pragma unroll
    for (int i = 0; i < 3; i++) {
      int a = (wr * 96 + 48 + i * 16 + r15) * 64 + b4 * 16;
      a ^= ((a >> 7) & 7) << 4;
      afr[i] = *(const bf16x8*)(As + a);
    }
    if (pf) stageB(kt + 3);
    asm volatile("" ::: "memory");
    __builtin_amdgcn_s_barrier();
    __builtin_amdgcn_s_setprio(1);
#pragma unroll
    for (int i = 0; i < 3; i++)
#pragma unroll
      for (int j = 0; j < 4; j++)
        acc[3 + i][j] = __builtin_amdgcn_mfma_f32_16x16x32_bf16(
            afr[i], bfr[j], acc[3 + i][j], 0, 0, 0);
    __builtin_amdgcn_s_setprio(0);
    const int rem = NKT - 2 - kt;
    if (tid < 256) {
      if (rem >= 2)      asm volatile("s_waitcnt vmcnt(8)" ::: "memory");
      else if (rem == 1) asm volatile("s_waitcnt vmcnt(4)" ::: "memory");
      else if (rem == 0) asm volatile("s_waitcnt vmcnt(0)" ::: "memory");
      else               asm volatile("" ::: "memory");
    } else {
      if (rem >= 2)      asm volatile("s_waitcnt vmcnt(6)" ::: "memory");
      else if (rem == 1) asm volatile("s_waitcnt vmcnt(3)" ::: "memory");
      else if (rem == 0) asm volatile("s_waitcnt vmcnt(0)" ::: "memory");
      else               asm volatile("" ::: "memory");
    }
    __builtin_amdgcn_s_barrier();
  }
  // ------------------- fused epilogue (192 rows) -------------------
  const int n0 = nb * 256;
  const int type = n0 / 1280;            // 0=Q 1=K 2=V
  const int cpart0 = n0 - type * 1280;
  if (type < 2) {
#pragma unroll
    for (int j = 0; j < 4; j++) {
      const int c = wc * 64 + j * 16 + r15;
      const int cp = cpart0 + c;
      const int h = cp / 80, p = cp % 80;
      const int d = (p >> 1) + (p & 1) * 40;
      const float bv = bias[type * 1280 + h * 80 + d];
      const int a = p >> 1;
#pragma unroll
      for (int i = 0; i < 6; i++) {
        const int sl = wr * 96 + i * 16 + b4 * 4;
        f32x4 cs4 = *(const f32x4*)&ctab[a * S + m0 + sl];
        f32x4 sn4 = *(const f32x4*)&stab[a * S + m0 + sl];
#pragma unroll
        for (int r = 0; r < 4; r++) {
          float v = acc[i][j][r] + bv;
          float ov = __shfl_xor(v, 1);
          float res = (p & 1) ? (v * cs4[r] + ov * sn4[r])
                              : (v * cs4[r] - ov * sn4[r]);
          if (type == 0) res *= QSCALE;
          *(bf16*)(lds + (sl + r) * 512 + ((2 * c) ^ (((sl + r) & 7) << 4))) =
              (bf16)res;
        }
      }
    }
    __syncthreads();
#pragma unroll
    for (int t = 0; t < 12; t++) {
      const int task = t * 512 + tid;
      const int sl = task >> 5, c = (task & 31) * 8;
      bf16x8 v = *(const bf16x8*)(lds + sl * 512 + ((2 * c) ^ ((sl & 7) << 4)));
      const int cp = cpart0 + c, h = cp / 80, p = cp % 80;
      bf16* dst = type ? Kb + ((size_t)h * S + m0 + sl) * KDP + p
                       : Qb + ((size_t)h * S + m0 + sl) * HD + p;
      *(bf16x8*)dst = v;
    }
  } else {
#pragma unroll
    for (int j = 0; j < 4; j++) {
      const int c = wc * 64 + j * 16 + r15;
      const float bv = bias[2560 + cpart0 + c];
#pragma unroll
      for (int i = 0; i < 6; i++) {
        const int sl = wr * 96 + i * 16 + b4 * 4;
#pragma unroll
        for (int r = 0; r < 4; r++) {
          *(bf16*)(lds + (sl + r) * 512 + ((2 * c) ^ swv(sl + r))) =
              (bf16)(acc[i][j][r] + bv);
        }
      }
    }
    __syncthreads();
#pragma unroll
    for (int t = 0; t < 12; t++) {
      const int task = t * 512 + tid;
      const int c = task & 255, s0 = (task >> 8) * 8;
      union { bf16 h[8]; bf16x8 v; } o;
#pragma unroll
      for (int e = 0; e < 8; e++)
        o.h[e] = *(const bf16*)(lds + (s0 + e) * 512 + ((2 * c) ^ swv(s0 + e)));
      const int cp = cpart0 + c, h = cp / 80, d = cp % 80;
      *(bf16x8*)(VTb + ((size_t)(h * 80 + d)) * S + m0 + s0) = o.v;
    }
  }
}

// --------------------------- proj GEMM (= R13) ------------------------------
__global__ __launch_bounds__(256) void gemm_proj(
    const bf16* __restrict__ A, const bf16* __restrict__ B,
    const float* __restrict__ bias, float* __restrict__ Cout, int M, int N,
    int K) {
  __shared__ bf16 Al[2][64 * 32];
  __shared__ bf16 Bl[2][128 * 32];
  const int tid = threadIdx.x;
  const int w = tid >> 6, lane = tid & 63;
  const int r15 = lane & 15, b4 = lane >> 4;
  const int nwg = gridDim.x * gridDim.y;
  const int orig = blockIdx.y * gridDim.x + blockIdx.x;
  const int swzid = (orig & 7) * (nwg >> 3) + (orig >> 3);
  const int bx = swzid % gridDim.x, by = swzid / gridDim.x;
  const int m0 = by * 64, n0 = bx * 128;
  const int wm = (w >> 1) * 32, wn = (w & 1) * 64;
  f32x4 acc[2][4] = {};
  const int row0 = tid >> 2, ko0 = (tid & 3) * 8;
  const bf16* Ar = A + (size_t)(m0 + row0) * K + ko0;
  const bf16* Br0 = B + (size_t)(n0 + row0) * K + ko0;
  const bf16* Br1 = B + (size_t)(n0 + row0 + 64) * K + ko0;

  auto stage = [&](int buf, int k0) {
    gload_lds16(Ar + k0, (char*)Al[buf] + tid * 16);
    gload_lds16(Br0 + k0, (char*)Bl[buf] + tid * 16);
    gload_lds16(Br1 + k0, (char*)Bl[buf] + 4096 + tid * 16);
  };

  stage(0, 0);
  int cur = 0;
  for (int k0 = 0; k0 < K; k0 += 32) {
    __syncthreads();
    if (k0 + 32 < K) stage(cur ^ 1, k0 + 32);
    bf16x8 af[2], bfr[4];
#pragma unroll
    for (int i = 0; i < 2; i++)
      af[i] = *(const bf16x8*)((const char*)Al[cur] + (wm + i * 16 + r15) * 64 + b4 * 16);
#pragma unroll
    for (int j = 0; j < 4; j++)
      bfr[j] = *(const bf16x8*)((const char*)Bl[cur] + (wn + j * 16 + r15) * 64 + b4 * 16);
#pragma unroll
    for (int i = 0; i < 2; i++)
#pragma unroll
      for (int j = 0; j < 4; j++)
        acc[i][j] = __builtin_amdgcn_mfma_f32_16x16x32_bf16(af[i], bfr[j], acc[i][j], 0, 0, 0);
    cur ^= 1;
  }
#pragma unroll
  for (int j = 0; j < 4; j++) {
    const int n = n0 + wn + j * 16 + r15;
    const float bv = bias[n];
#pragma unroll
    for (int i = 0; i < 2; i++) {
      const int mr = m0 + wm + i * 16 + b4 * 4;
#pragma unroll
      for (int r = 0; r < 4; r++)
        Cout[(size_t)(mr + r) * N + n] = acc[i][j][r] + bv;
    }
  }
}

// --------------------------- flash attention (split-key + counted vmcnt) ----
// Block: QBLK=64, 4 waves = 2 key-pairs, even/odd 64-key tiles, private LDS.
// Per tile: stage K(8)+V(5) -> vmcnt(5) -> bar -> QK+softmax (V in flight)
// -> vmcnt(0) -> bar -> PV -> lgkmcnt(0)+bar (buffer reuse).
__global__ __launch_bounds__(256, 3) void attn_kern(
    const bf16* __restrict__ Qg, const bf16* __restrict__ Kg,
    const bf16* __restrict__ Vg, const int* __restrict__ cu, int nseg,
    bf16* __restrict__ Out) {
  __shared__ bf16 Kl[2][64 * 128];  // per pair, [key][128], swz ((row&15)<<4)
  __shared__ bf16 Vl[2][80 * 64];   // per pair, [d][64],   swz ((row&7)<<4)
  const int tid = threadIdx.x, w = tid >> 6, lane = tid & 63;
  const int r31 = lane & 31, hi = lane >> 5;
  const int pair = w >> 1, qs = w & 1;
  const int pt = tid & 127;
  const int nwg = gridDim.x;  // 768
  const int orig = blockIdx.x;
  const int swzb = (orig & 7) * (nwg >> 3) + (orig >> 3);
  const int h = swzb / 48, qb = swzb % 48;
  const int q = qb * 64 + qs * 32 + r31;
  int sq = 0, eq = S, lo = 0, hik = S;
  {
    const int qlo = qb * 64, qhi = qb * 64 + 63;
#pragma unroll
    for (int i = 0; i < 8; i++) {
      if (i >= nseg) break;
      int a = cu[i], b = cu[i + 1];
      if (q >= a && q < b) { sq = a; eq = b; }
      if (qlo >= a && qlo < b) lo = a;
      if (qhi >= a && qhi < b) hik = b;
    }
  }
  bf16x8 qf[5];
  {
    const bf16* qrow = Qg + ((size_t)h * S + q) * HD + hi * 8;
#pragma unroll
    for (int kk = 0; kk < 5; kk++) qf[kk] = *(const bf16x8*)(qrow + kk * 16);
  }
  int kdst[8], ksrc[8], vdst[5], vsrc[5];
#pragma unroll
  for (int c = 0; c < 8; c++) {
    int lin = (c * 128 + pt) * 16;
    int row = lin >> 8, colb = (lin & 255) ^ ((row & 15) << 4);
    kdst[c] = lin; ksrc[c] = row * KDP + colb / 2;
  }
#pragma unroll
  for (int c = 0; c < 5; c++) {
    int lin = (c * 128 + pt) * 16;
    int row = lin >> 7, colb = (lin & 127) ^ ((row & 7) << 4);
    vdst[c] = lin; vsrc[c] = row * S + colb / 2;
  }
  const bf16* Kbase = Kg + (size_t)h * S * KDP;
  const bf16* Vbase = Vg + (size_t)h * HD * S;
  char* Klp = (char*)Kl[pair];
  char* Vlp = (char*)Vl[pair];
  auto stage = [&](int k0) {
#pragma unroll
    for (int c = 0; c < 8; c++)
      gload_lds16(Kbase + (size_t)k0 * KDP + ksrc[c], Klp + kdst[c]);
#pragma unroll
    for (int c = 0; c < 5; c++)
      gload_lds16(Vbase + vsrc[c] + k0, Vlp + vdst[c]);
  };
  f32x16 o0 = {}, o1 = {}, o2 = {};
  float m = -1e30f, l = 0.f;
  const int nt = (hik - lo) >> 6;
  const int nit = (nt + 1) >> 1;
  for (int i = 0; i < nit; ++i) {
    const int t = 2 * i + pair;
    const bool act = t < nt;
    const int k0 = lo + t * 64;
    // buffer-free: my pair's PV ds_reads of prev tile complete
    asm volatile("s_waitcnt lgkmcnt(0)" ::: "memory");
    __builtin_amdgcn_s_barrier();
    if (act) stage(k0);  // 8 K loads then 5 V loads
    asm volatile("s_waitcnt vmcnt(5)" ::: "memory");  // K resident
    __builtin_amdgcn_s_barrier();
    f32x16 st0 = {}, st1 = {};
    float rs = 0.f;
    u32 wd0[4][2], wd1[4][2];
    if (act) {
      // ---- S^T = K * Q^T (V loads still in flight) ----
      __builtin_amdgcn_s_setprio(1);
#pragma unroll
      for (int kk = 0; kk < 5; kk++) {
        const int colb = kk * 32 + hi * 16;
        bf16x8 kf0 = *(const bf16x8*)(Klp + r31 * 256 + (colb ^ ((r31 & 15) << 4)));
        bf16x8 kf1 = *(const bf16x8*)(Klp + (32 + r31) * 256 + (colb ^ ((r31 & 15) << 4)));
        st0 = __builtin_amdgcn_mfma_f32_32x32x16_bf16(kf0, qf[kk], st0, 0, 0, 0);
        st1 = __builtin_amdgcn_mfma_f32_32x32x16_bf16(kf1, qf[kk], st1, 0, 0, 0);
      }
      __builtin_amdgcn_s_setprio(0);
      float tm = -3e38f;
      if (k0 >= sq && k0 + 63 < eq) {
#pragma unroll
        for (int j = 0; j < 16; j++) {
          tm = fmaxf(tm, st0[j]);
          tm = fmaxf(tm, st1[j]);
        }
      } else {
#pragma unroll
        for (int j = 0; j < 16; j++) {
          const int crow = (j & 3) + 8 * (j >> 2) + 4 * hi;
          int key0 = k0 + crow, key1 = k0 + 32 + crow;
          st0[j] = (key0 >= sq && key0 < eq) ? st0[j] : -1e30f;
          st1[j] = (key1 >= sq && key1 < eq) ? st1[j] : -1e30f;
          tm = fmaxf(tm, st0[j]);
          tm = fmaxf(tm, st1[j]);
        }
      }
      tm = fmaxf(tm, __shfl_xor(tm, 32));
      if (!__all(tm <= m + 8.f)) {  // defer-max
        const float mn = fmaxf(m, tm);
        const float alpha = __builtin_amdgcn_exp2f(m - mn);
        o0 *= alpha; o1 *= alpha; o2 *= alpha;
        l *= alpha;
        m = mn;
      }
#pragma unroll
      for (int g2 = 0; g2 < 4; g2++) {
#pragma unroll
        for (int hh = 0; hh < 2; hh++) {
          float a0 = __builtin_amdgcn_exp2f(st0[g2 * 4 + 2 * hh] - m);
          float a1 = __builtin_amdgcn_exp2f(st0[g2 * 4 + 2 * hh + 1] - m);
          float b0 = __builtin_amdgcn_exp2f(st1[g2 * 4 + 2 * hh] - m);
          float b1 = __builtin_amdgcn_exp2f(st1[g2 * 4 + 2 * hh + 1] - m);
          rs += a0 + a1 + b0 + b1;
          wd0[g2][hh] = pkbf2(a0, a1);
          wd1[g2][hh] = pkbf2(b0, b1);
        }
      }
      rs += __shfl_xor(rs, 32);
      l += rs;
    }
    asm volatile("s_waitcnt vmcnt(0)" ::: "memory");  // V resident
    __builtin_amdgcn_s_barrier();
    if (act) {
      // ---- O^T += V^T * P^T ----
      __builtin_amdgcn_s_setprio(1);
#pragma unroll
      for (int kk = 0; kk < 4; kk++) {
        const int g2o = (kk & 1) * 2 + hi;
        const int g2s = (kk & 1) * 2 + (hi ^ 1);
        u32 own0, own1, snd0, snd1;
        if (kk < 2) {
          own0 = wd0[g2o][0]; own1 = wd0[g2o][1];
          snd0 = wd0[g2s][0]; snd1 = wd0[g2s][1];
        } else {
          own0 = wd1[g2o][0]; own1 = wd1[g2o][1];
          snd0 = wd1[g2s][0]; snd1 = wd1[g2s][1];
        }
        u32 rc0 = (u32)__shfl_xor((int)snd0, 32);
        u32 rc1 = (u32)__shfl_xor((int)snd1, 32);
        union { u32 w[4]; bf16x8 v; } pf;
        if (hi == 0) { pf.w[0] = own0; pf.w[1] = own1; pf.w[2] = rc0; pf.w[3] = rc1; }
        else         { pf.w[0] = rc0;  pf.w[1] = rc1;  pf.w[2] = own0; pf.w[3] = own1; }
        const int colb = kk * 32 + hi * 16;
#pragma unroll
        for (int mt = 0; mt < 3; mt++) {
          int row = mt * 32 + r31;
          row = row < HD ? row : 0;
          bf16x8 vf = *(const bf16x8*)(Vlp + row * 128 + (colb ^ ((row & 7) << 4)));
          f32x16* op = mt == 0 ? &o0 : (mt == 1 ? &o1 : &o2);
          *op = __builtin_amdgcn_mfma_f32_32x32x16_bf16(vf, pf.v, *op, 0, 0, 0);
        }
      }
      __builtin_amdgcn_s_setprio(0);
    }
  }
  // ---- merge pair states: pair1 -> LDS, pair0 merges + stores ----
  __syncthreads();
  float* mb = (float*)Kl;
  if (pair == 1) {
    float* d = mb + ((size_t)qs * 64 + lane) * 50;
    d[0] = m; d[1] = l;
#pragma unroll
    for (int j = 0; j < 16; j++) { d[2 + j] = o0[j]; d[18 + j] = o1[j]; d[34 + j] = o2[j]; }
  }
  __syncthreads();
  if (pair == 0) {
    const float* d = mb + ((size_t)qs * 64 + lane) * 50;
    const float pm = d[0], pl = d[1];
    const float mn = fmaxf(m, pm);
    const float a = __builtin_amdgcn_exp2f(m - mn);
    const float b = __builtin_amdgcn_exp2f(pm - mn);
    const float lt = l * a + pl * b;
    const float inv = 1.f / lt;
    bf16* orow = Out + (size_t)q * DIM + h * HD;
#pragma unroll
    for (int rg = 0; rg < 4; rg++) {
      bf16x4 v0, v1;
#pragma unroll
      for (int e = 0; e < 4; e++) {
        v0[e] = (bf16)((o0[rg * 4 + e] * a + d[2 + rg * 4 + e] * b) * inv);
        v1[e] = (bf16)((o1[rg * 4 + e] * a + d[18 + rg * 4 + e] * b) * inv);
      }
      *(bf16x4*)(orow + 8 * rg + 4 * hi) = v0;
      *(bf16x4*)(orow + 32 + 8 * rg + 4 * hi) = v1;
    }
#pragma unroll
    for (int rg = 0; rg < 2; rg++) {
      bf16x4 v2;
#pragma unroll
      for (int e = 0; e < 4; e++)
        v2[e] = (bf16)((o2[rg * 4 + e] * a + d[34 + rg * 4 + e] * b) * inv);
      *(bf16x4*)(orow + 64 + 8 * rg + 4 * hi) = v2;
    }
  }
}

// --------------------------- launch -----------------------------------------
extern "C" void kernel_launch(void* const* d_in, const int* in_sizes, int n_in,
                              void* d_out, int out_size, void* d_ws,
                              size_t ws_size, hipStream_t stream) {
  const float* x = (const float*)d_in[0];
  const int* cu = (const int*)d_in[1];
  const float* rope = (const float*)d_in[2];
  const float* w_qkv = (const float*)d_in[3];
  const float* b_qkv = (const float*)d_in[4];
  const float* w_proj = (const float*)d_in[5];
  const float* b_proj = (const float*)d_in[6];
  const int nseg = in_sizes[1] - 1;

  bf16* pA = (bf16*)d_ws;                          // dead after gemm256
  bf16* pB = pA + (size_t)S * DIM;
  bf16* wp16 = pB + (size_t)NQKV * DIM;
  bf16* Qb = wp16 + (size_t)DIM * DIM;             // H*S*80
  bf16* Kb = Qb + (size_t)H * S * HD;              // H*S*128
  bf16* VTb = Kb + (size_t)H * S * KDP;            // H*80*S
  float* ctab = (float*)(VTb + (size_t)H * HD * S);
  float* stab = ctab + (size_t)S * 40;
  bf16* attn16 = pA;                               // alias dead pA

  pack_inputs<<<(int)(TOT_CHUNKS / 256), 256, 0, stream>>>(
      x, w_qkv, w_proj, rope, pA, pB, wp16, Kb, ctab, stab);
  gemm256<<<dim3(NB_B, MB_A), 512, 114688, stream>>>(
      pA, pB, b_qkv, ctab, stab, Qb, Kb, VTb);
  attn_kern<<<H * 48, 256, 0, stream>>>(Qb, Kb, VTb, cu, nseg, attn16);
  gemm_proj<<<dim3(DIM / 128, S / 64), 256, 0, stream>>>(
      attn16, wp16, b_proj, (float*)d_out, S, DIM, DIM);
}

// Round 16
// 105.944 us; speedup vs baseline: 1.1160x; 1.0435x over previous
//
#include <hip/hip_runtime.h>

// ---------------------------------------------------------------------------
// Attention block, MI355X bf16-MFMA implementation.  R16 (= R15 + proj ring):
//  - gemm_proj rebuilt on the gemm256 recipe: 4-slot ring (48KB -> 2+ blk/CU),
//    counted vmcnt(6/3/0), involution XOR swizzle w/ pre-swizzled sources
//    (kills the 8-way LDS bank conflict of the old linear layout), setprio.
//  - gemm256 / pack / attn(split-key + counted vmcnt): byte-identical to R15.
// ---------------------------------------------------------------------------

typedef __bf16 bf16;
typedef __bf16 bf16x4 __attribute__((ext_vector_type(4)));
typedef __bf16 bf16x8 __attribute__((ext_vector_type(8)));
typedef float f32x4 __attribute__((ext_vector_type(4)));
typedef float f32x16 __attribute__((ext_vector_type(16)));
typedef unsigned int u32;

constexpr int S = 3072;
constexpr int DIM = 1280;
constexpr int H = 16;
constexpr int HD = 80;
constexpr int KDP = 128;        // K head-dim padded (row stride)
constexpr int NQKV = 3 * DIM;   // 3840

constexpr int BM = 192;
constexpr int MB_A = S / BM;     // 16 panels
constexpr int NB_B = NQKV / 256; // 15
constexpr int NKT = DIM / 32;    // 40
constexpr int ASL = BM * 32 * 2;     // 12288 B per A slice
constexpr int SLOT = ASL + 16384;    // 28672 B per ring slot

// log2(e) / sqrt(80): folded into Q so scores are in exp2 domain.
constexpr float QSCALE = 1.4426950408889634f / 8.94427190999916f;

__device__ __forceinline__ void gload_lds16(const void* g, void* l) {
  __builtin_amdgcn_global_load_lds(
      (const __attribute__((address_space(1))) void*)g,
      (__attribute__((address_space(3))) void*)l, 16, 0, 0);
}

__device__ __forceinline__ u32 pkbf2(float a, float b) {
  union { bf16 h[2]; u32 w; } u;
  u.h[0] = (bf16)a; u.h[1] = (bf16)b;
  return u.w;
}

__device__ __forceinline__ int swv(int s) {
  return ((((s >> 3) & 31) ^ ((s & 7) << 2)) << 2);
}

// --------------------------- input packing (= R15) --------------------------
constexpr long PA_CHUNKS = (long)MB_A * NKT * (ASL / 16);  // 491520
constexpr long PB_CHUNKS = (long)NB_B * NKT * 1024;        // 614400
constexpr long PW_CHUNKS = (long)DIM * DIM / 8;            // 204800
constexpr long KP_CHUNKS = (long)H * S * 48 / 8;           // 294912
constexpr long CS_CHUNKS = (long)S * 40 / 8;               // 15360
constexpr long TOT_CHUNKS = PA_CHUNKS + PB_CHUNKS + PW_CHUNKS + KP_CHUNKS + CS_CHUNKS;

__global__ __launch_bounds__(256) void pack_inputs(
    const float* __restrict__ x, const float* __restrict__ wq,
    const float* __restrict__ wp, const float* __restrict__ rope,
    bf16* __restrict__ pA, bf16* __restrict__ pB, bf16* __restrict__ wp16,
    bf16* __restrict__ Kb, float* __restrict__ ctab, float* __restrict__ stab) {
  long t = (long)blockIdx.x * 256 + threadIdx.x;
  if (t < PA_CHUNKS) {
    const int blk = (int)(t / (NKT * 768)), rem = (int)(t % (NKT * 768));
    const int kt = rem / 768, c = rem - kt * 768;
    const int lin = c * 16;
    const int logi = lin ^ (((lin >> 7) & 7) << 4);
    const int row = logi >> 6, col = (logi & 63) >> 1;
    const float* src = x + (size_t)(blk * BM + row) * DIM + kt * 32 + col;
    float4 v0 = *(const float4*)src;
    float4 v1 = *(const float4*)(src + 4);
    bf16x8 o = {(bf16)v0.x, (bf16)v0.y, (bf16)v0.z, (bf16)v0.w,
                (bf16)v1.x, (bf16)v1.y, (bf16)v1.z, (bf16)v1.w};
    *(bf16x8*)(pA + t * 8) = o;
  } else if (t < PA_CHUNKS + PB_CHUNKS) {
    long t2 = t - PA_CHUNKS;
    const int blk = (int)(t2 / (NKT * 1024)), rem = (int)(t2 % (NKT * 1024));
    const int kt = rem >> 10, c = rem & 1023;
    const int lin = c * 16;
    const int logi = lin ^ (((lin >> 7) & 7) << 4);
    const int row = logi >> 6, col = (logi & 63) >> 1;
    int grow = blk * 256 + row;
    if (grow < 2560) {  // permute q/k rows: pairs adjacent
      const int ty = grow / 1280, rm = grow % 1280;
      const int h = rm / 80, p = rm % 80;
      grow = ty * 1280 + h * 80 + (p >> 1) + (p & 1) * 40;
    }
    const float* src = wq + (size_t)grow * DIM + kt * 32 + col;
    float4 v0 = *(const float4*)src;
    float4 v1 = *(const float4*)(src + 4);
    bf16x8 o = {(bf16)v0.x, (bf16)v0.y, (bf16)v0.z, (bf16)v0.w,
                (bf16)v1.x, (bf16)v1.y, (bf16)v1.z, (bf16)v1.w};
    *(bf16x8*)(pB + t2 * 8) = o;
  } else if (t < PA_CHUNKS + PB_CHUNKS + PW_CHUNKS) {
    long t2 = t - PA_CHUNKS - PB_CHUNKS;
    const float* src = wp + t2 * 8;
    float4 v0 = *(const float4*)src;
    float4 v1 = *(const float4*)(src + 4);
    bf16x8 o = {(bf16)v0.x, (bf16)v0.y, (bf16)v0.z, (bf16)v0.w,
                (bf16)v1.x, (bf16)v1.y, (bf16)v1.z, (bf16)v1.w};
    *(bf16x8*)(wp16 + t2 * 8) = o;
  } else if (t < PA_CHUNKS + PB_CHUNKS + PW_CHUNKS + KP_CHUNKS) {
    long t2 = t - PA_CHUNKS - PB_CHUNKS - PW_CHUNKS;
    const int h = (int)(t2 / (S * 6)), r = (int)(t2 % (S * 6));
    const int s = r / 6, cc = r % 6;
    bf16x8 z = {};
    *(bf16x8*)(Kb + ((size_t)h * S + s) * KDP + 80 + cc * 8) = z;
  } else {
    long t3 = t - PA_CHUNKS - PB_CHUNKS - PW_CHUNKS - KP_CHUNKS;
#pragma unroll
    for (int k = 0; k < 8; k++) {
      const int idx = (int)(t3 * 8 + k);
      const int s = idx / 40, a = idx % 40;
      float sn, cs;
      __sincosf(rope[idx], &sn, &cs);
      ctab[a * S + s] = cs;
      stab[a * S + s] = sn;
    }
  }
}

// --------------------------- fused QKV GEMM + rope/scatter (= R15) ----------
__global__ __launch_bounds__(512, 2) void gemm256(
    const bf16* __restrict__ pA, const bf16* __restrict__ pB,
    const float* __restrict__ bias, const float* __restrict__ ctab,
    const float* __restrict__ stab, bf16* __restrict__ Qb,
    bf16* __restrict__ Kb, bf16* __restrict__ VTb) {
  extern __shared__ char lds[];
  const int tid = threadIdx.x;
  const int w = tid >> 6, lane = tid & 63;
  const int r15 = lane & 15, b4 = lane >> 4;
  const int wr = w >> 2, wc = w & 3;
  const int nwg = gridDim.x * gridDim.y;  // 240
  const int orig = blockIdx.y * gridDim.x + blockIdx.x;
  const int xcd = orig % 8, loc = orig / 8;
  const int qq = nwg / 8, rq = nwg % 8;
  const int swzid =
      (xcd < rq ? xcd * (qq + 1) : rq * (qq + 1) + (xcd - rq) * qq) + loc;
  const int nb = swzid % gridDim.x, mb = swzid / gridDim.x;
  const int m0 = mb * BM;
  const char* aPanel = (const char*)pA + (size_t)mb * NKT * ASL;
  const char* bPanel = (const char*)pB + (size_t)nb * NKT * 16384;
  auto stageA = [&](int kt) {
    char* s = lds + (kt & 3) * SLOT;
    const char* g = aPanel + (size_t)kt * ASL;
    gload_lds16(g + tid * 16, s + tid * 16);
    if (tid < 256)
      gload_lds16(g + 8192 + tid * 16, s + 8192 + tid * 16);
  };
  auto stageB = [&](int kt) {
    char* s = lds + (kt & 3) * SLOT + ASL;
    const char* g = bPanel + (size_t)kt * 16384;
    gload_lds16(g + tid * 16, s + tid * 16);
    gload_lds16(g + 8192 + tid * 16, s + 8192 + tid * 16);
  };
  f32x4 acc[6][4] = {};
  stageA(0); stageB(0); stageA(1); stageB(1); stageA(2); stageB(2);
  if (tid < 256) asm volatile("s_waitcnt vmcnt(8)" ::: "memory");
  else           asm volatile("s_waitcnt vmcnt(6)" ::: "memory");
  __builtin_amdgcn_s_barrier();
  for (int kt = 0; kt < NKT; ++kt) {
    const char* As = lds + (kt & 3) * SLOT;
    const char* Bs = As + ASL;
    const bool pf = (kt + 3 < NKT);
    bf16x8 afr[3], bfr[4];
#pragma unroll
    for (int i = 0; i < 3; i++) {
      int a = (wr * 96 + i * 16 + r15) * 64 + b4 * 16;
      a ^= ((a >> 7) & 7) << 4;
      afr[i] = *(const bf16x8*)(As + a);
    }
#pragma unroll
    for (int j = 0; j < 4; j++) {
      int a = (wc * 64 + j * 16 + r15) * 64 + b4 * 16;
      a ^= ((a >> 7) & 7) << 4;
      bfr[j] = *(const bf16x8*)(Bs + a);
    }
    if (pf) stageA(kt + 3);
    asm volatile("" ::: "memory");
    __builtin_amdgcn_s_barrier();
    __builtin_amdgcn_s_setprio(1);
#pragma unroll
    for (int i = 0; i < 3; i++)
#pragma unroll
      for (int j = 0; j < 4; j++)
        acc[i][j] = __builtin_amdgcn_mfma_f32_16x16x32_bf16(afr[i], bfr[j],
                                                            acc[i][j], 0, 0, 0);
    __builtin_amdgcn_s_setprio(0);
    asm volatile("" ::: "memory");
    __builtin_amdgcn_s_barrier();
#pragma unroll
    for (int i = 0; i < 3; i++) {
      int a = (wr * 96 + 48 + i * 16 + r15) * 64 + b4 * 16;
      a ^= ((a >> 7) & 7) << 4;
      afr[i] = *(const bf16x8*)(As + a);
    }
    if (pf) stageB(kt + 3);
    asm volatile("" ::: "memory");
    __builtin_amdgcn_s_barrier();
    __builtin_amdgcn_s_setprio(1);
#pragma unroll
    for (int i = 0; i < 3; i++)
#pragma unroll
      for (int j = 0; j < 4; j++)
        acc[3 + i][j] = __builtin_amdgcn_mfma_f32_16x16x32_bf16(
            afr[i], bfr[j], acc[3 + i][j], 0, 0, 0);
    __builtin_amdgcn_s_setprio(0);
    const int rem = NKT - 2 - kt;
    if (tid < 256) {
      if (rem >= 2)      asm volatile("s_waitcnt vmcnt(8)" ::: "memory");
      else if (rem == 1) asm volatile("s_waitcnt vmcnt(4)" ::: "memory");
      else if (rem == 0) asm volatile("s_waitcnt vmcnt(0)" ::: "memory");
      else               asm volatile("" ::: "memory");
    } else {
      if (rem >= 2)      asm volatile("s_waitcnt vmcnt(6)" ::: "memory");
      else if (rem == 1) asm volatile("s_waitcnt vmcnt(3)" ::: "memory");
      else if (rem == 0) asm volatile("s_waitcnt vmcnt(0)" ::: "memory");
      else               asm volatile("" ::: "memory");
    }
    __builtin_amdgcn_s_barrier();
  }
  // ------------------- fused epilogue (192 rows) -------------------
  const int n0 = nb * 256;
  const int type = n0 / 1280;            // 0=Q 1=K 2=V
  const int cpart0 = n0 - type * 1280;
  if (type < 2) {
#pragma unroll
    for (int j = 0; j < 4; j++) {
      const int c = wc * 64 + j * 16 + r15;
      const int cp = cpart0 + c;
      const int h = cp / 80, p = cp % 80;
      const int d = (p >> 1) + (p & 1) * 40;
      const float bv = bias[type * 1280 + h * 80 + d];
      const int a = p >> 1;
#pragma unroll
      for (int i = 0; i < 6; i++) {
        const int sl = wr * 96 + i * 16 + b4 * 4;
        f32x4 cs4 = *(const f32x4*)&ctab[a * S + m0 + sl];
        f32x4 sn4 = *(const f32x4*)&stab[a * S + m0 + sl];
#pragma unroll
        for (int r = 0; r < 4; r++) {
          float v = acc[i][j][r] + bv;
          float ov = __shfl_xor(v, 1);
          float res = (p & 1) ? (v * cs4[r] + ov * sn4[r])
                              : (v * cs4[r] - ov * sn4[r]);
          if (type == 0) res *= QSCALE;
          *(bf16*)(lds + (sl + r) * 512 + ((2 * c) ^ (((sl + r) & 7) << 4))) =
              (bf16)res;
        }
      }
    }
    __syncthreads();
#pragma unroll
    for (int t = 0; t < 12; t++) {
      const int task = t * 512 + tid;
      const int sl = task >> 5, c = (task & 31) * 8;
      bf16x8 v = *(const bf16x8*)(lds + sl * 512 + ((2 * c) ^ ((sl & 7) << 4)));
      const int cp = cpart0 + c, h = cp / 80, p = cp % 80;
      bf16* dst = type ? Kb + ((size_t)h * S + m0 + sl) * KDP + p
                       : Qb + ((size_t)h * S + m0 + sl) * HD + p;
      *(bf16x8*)dst = v;
    }
  } else {
#pragma unroll
    for (int j = 0; j < 4; j++) {
      const int c = wc * 64 + j * 16 + r15;
      const float bv = bias[2560 + cpart0 + c];
#pragma unroll
      for (int i = 0; i < 6; i++) {
        const int sl = wr * 96 + i * 16 + b4 * 4;
#pragma unroll
        for (int r = 0; r < 4; r++) {
          *(bf16*)(lds + (sl + r) * 512 + ((2 * c) ^ swv(sl + r))) =
              (bf16)(acc[i][j][r] + bv);
        }
      }
    }
    __syncthreads();
#pragma unroll
    for (int t = 0; t < 12; t++) {
      const int task = t * 512 + tid;
      const int c = task & 255, s0 = (task >> 8) * 8;
      union { bf16 h[8]; bf16x8 v; } o;
#pragma unroll
      for (int e = 0; e < 8; e++)
        o.h[e] = *(const bf16*)(lds + (s0 + e) * 512 + ((2 * c) ^ swv(s0 + e)));
      const int cp = cpart0 + c, h = cp / 80, d = cp % 80;
      *(bf16x8*)(VTb + ((size_t)(h * 80 + d)) * S + m0 + s0) = o.v;
    }
  }
}

// --------------------------- proj GEMM: 64x128, 4-slot ring -----------------
// C[m][n] = sum_k A[m][k]*B[n][k] + bias[n], fp32 out.  12KB/slot x4 = 48KB
// (2+ blocks/CU), counted vmcnt(6/3/0), involution swizzle (pre-swizzled
// scattered sources), setprio.  Grid 480 (%8==0).  Wave = 32x64, acc[2][4].
__global__ __launch_bounds__(256) void gemm_proj(
    const bf16* __restrict__ A, const bf16* __restrict__ B,
    const float* __restrict__ bias, float* __restrict__ Cout, int M, int N,
    int K) {
  extern __shared__ char plds[];  // 4 x (4KB A + 8KB B)
  const int tid = threadIdx.x;
  const int w = tid >> 6, lane = tid & 63;
  const int r15 = lane & 15, b4 = lane >> 4;
  const int wm = (w >> 1) * 32, wn = (w & 1) * 64;
  const int nwg = gridDim.x * gridDim.y;  // 480
  const int orig = blockIdx.y * gridDim.x + blockIdx.x;
  const int swzid = (orig & 7) * (nwg >> 3) + (orig >> 3);
  const int bx = swzid % gridDim.x, by = swzid / gridDim.x;
  const int m0 = by * 64, n0 = bx * 128;
  // pre-swizzled source coordinates (linear LDS dest, per rule 21)
  int aR, aC, bR[2], bC[2];
  {
    const int lin = tid * 16;
    const int logi = lin ^ (((lin >> 7) & 7) << 4);
    aR = logi >> 6; aC = (logi & 63) >> 1;
  }
#pragma unroll
  for (int i = 0; i < 2; i++) {
    const int lin = tid * 16 + i * 4096;
    const int logi = lin ^ (((lin >> 7) & 7) << 4);
    bR[i] = logi >> 6; bC[i] = (logi & 63) >> 1;
  }
  const int NT = K / 32;  // 40
  auto stage = [&](int kt) {
    char* s = plds + (kt & 3) * 12288;
    gload_lds16(A + (size_t)(m0 + aR) * K + kt * 32 + aC, s + tid * 16);
#pragma unroll
    for (int i = 0; i < 2; i++)
      gload_lds16(B + (size_t)(n0 + bR[i]) * K + kt * 32 + bC[i],
                  s + 4096 + i * 4096 + tid * 16);
  };
  f32x4 acc[2][4] = {};
  stage(0); stage(1); stage(2);
  asm volatile("s_waitcnt vmcnt(6)" ::: "memory");  // slice 0 resident
  __builtin_amdgcn_s_barrier();
  for (int kt = 0; kt < NT; ++kt) {
    const char* As = plds + (kt & 3) * 12288;
    const char* Bs = As + 4096;
    bf16x8 af[2], bfr[4];
#pragma unroll
    for (int i = 0; i < 2; i++) {
      int a = (wm + i * 16 + r15) * 64 + b4 * 16;
      a ^= ((a >> 7) & 7) << 4;
      af[i] = *(const bf16x8*)(As + a);
    }
#pragma unroll
    for (int j = 0; j < 4; j++) {
      int a = (wn + j * 16 + r15) * 64 + b4 * 16;
      a ^= ((a >> 7) & 7) << 4;
      bfr[j] = *(const bf16x8*)(Bs + a);
    }
    if (kt + 3 < NT) stage(kt + 3);
    asm volatile("" ::: "memory");
    __builtin_amdgcn_s_barrier();
    __builtin_amdgcn_s_setprio(1);
#pragma unroll
    for (int i = 0; i < 2; i++)
#pragma unroll
      for (int j = 0; j < 4; j++)
        acc[i][j] = __builtin_amdgcn_mfma_f32_16x16x32_bf16(af[i], bfr[j],
                                                            acc[i][j], 0, 0, 0);
    __builtin_amdgcn_s_setprio(0);
    const int rem = NT - 2 - kt;
    if (rem >= 2)      asm volatile("s_waitcnt vmcnt(6)" ::: "memory");
    else if (rem == 1) asm volatile("s_waitcnt vmcnt(3)" ::: "memory");
    else if (rem == 0) asm volatile("s_waitcnt vmcnt(0)" ::: "memory");
    else               asm volatile("" ::: "memory");
    __builtin_amdgcn_s_barrier();
  }
#pragma unroll
  for (int j = 0; j < 4; j++) {
    const int n = n0 + wn + j * 16 + r15;
    const float bv = bias[n];
#pragma unroll
    for (int i = 0; i < 2; i++) {
      const int mr = m0 + wm + i * 16 + b4 * 4;
#pragma unroll
      for (int r = 0; r < 4; r++)
        Cout[(size_t)(mr + r) * N + n] = acc[i][j][r] + bv;
    }
  }
}

// --------------------------- flash attention (= R15) ------------------------
__global__ __launch_bounds__(256, 3) void attn_kern(
    const bf16* __restrict__ Qg, const bf16* __restrict__ Kg,
    const bf16* __restrict__ Vg, const int* __restrict__ cu, int nseg,
    bf16* __restrict__ Out) {
  __shared__ bf16 Kl[2][64 * 128];
  __shared__ bf16 Vl[2][80 * 64];
  const int tid = threadIdx.x, w = tid >> 6, lane = tid & 63;
  const int r31 = lane & 31, hi = lane >> 5;
  const int pair = w >> 1, qs = w & 1;
  const int pt = tid & 127;
  const int nwg = gridDim.x;
  const int orig = blockIdx.x;
  const int swzb = (orig & 7) * (nwg >> 3) + (orig >> 3);
  const int h = swzb / 48, qb = swzb % 48;
  const int q = qb * 64 + qs * 32 + r31;
  int sq = 0, eq = S, lo = 0, hik = S;
  {
    const int qlo = qb * 64, qhi = qb * 64 + 63;
#pragma unroll
    for (int i = 0; i < 8; i++) {
      if (i >= nseg) break;
      int a = cu[i], b = cu[i + 1];
      if (q >= a && q < b) { sq = a; eq = b; }
      if (qlo >= a && qlo < b) lo = a;
      if (qhi >= a && qhi < b) hik = b;
    }
  }
  bf16x8 qf[5];
  {
    const bf16* qrow = Qg + ((size_t)h * S + q) * HD + hi * 8;
#pragma unroll
    for (int kk = 0; kk < 5; kk++) qf[kk] = *(const bf16x8*)(qrow + kk * 16);
  }
  int kdst[8], ksrc[8], vdst[5], vsrc[5];
#pragma unroll
  for (int c = 0; c < 8; c++) {
    int lin = (c * 128 + pt) * 16;
    int row = lin >> 8, colb = (lin & 255) ^ ((row & 15) << 4);
    kdst[c] = lin; ksrc[c] = row * KDP + colb / 2;
  }
#pragma unroll
  for (int c = 0; c < 5; c++) {
    int lin = (c * 128 + pt) * 16;
    int row = lin >> 7, colb = (lin & 127) ^ ((row & 7) << 4);
    vdst[c] = lin; vsrc[c] = row * S + colb / 2;
  }
  const bf16* Kbase = Kg + (size_t)h * S * KDP;
  const bf16* Vbase = Vg + (size_t)h * HD * S;
  char* Klp = (char*)Kl[pair];
  char* Vlp = (char*)Vl[pair];
  auto stage = [&](int k0) {
#pragma unroll
    for (int c = 0; c < 8; c++)
      gload_lds16(Kbase + (size_t)k0 * KDP + ksrc[c], Klp + kdst[c]);
#pragma unroll
    for (int c = 0; c < 5; c++)
      gload_lds16(Vbase + vsrc[c] + k0, Vlp + vdst[c]);
  };
  f32x16 o0 = {}, o1 = {}, o2 = {};
  float m = -1e30f, l = 0.f;
  const int nt = (hik - lo) >> 6;
  const int nit = (nt + 1) >> 1;
  for (int i = 0; i < nit; ++i) {
    const int t = 2 * i + pair;
    const bool act = t < nt;
    const int k0 = lo + t * 64;
    asm volatile("s_waitcnt lgkmcnt(0)" ::: "memory");
    __builtin_amdgcn_s_barrier();
    if (act) stage(k0);
    asm volatile("s_waitcnt vmcnt(5)" ::: "memory");
    __builtin_amdgcn_s_barrier();
    f32x16 st0 = {}, st1 = {};
    float rs = 0.f;
    u32 wd0[4][2], wd1[4][2];
    if (act) {
      __builtin_amdgcn_s_setprio(1);
#pragma unroll
      for (int kk = 0; kk < 5; kk++) {
        const int colb = kk * 32 + hi * 16;
        bf16x8 kf0 = *(const bf16x8*)(Klp + r31 * 256 + (colb ^ ((r31 & 15) << 4)));
        bf16x8 kf1 = *(const bf16x8*)(Klp + (32 + r31) * 256 + (colb ^ ((r31 & 15) << 4)));
        st0 = __builtin_amdgcn_mfma_f32_32x32x16_bf16(kf0, qf[kk], st0, 0, 0, 0);
        st1 = __builtin_amdgcn_mfma_f32_32x32x16_bf16(kf1, qf[kk], st1, 0, 0, 0);
      }
      __builtin_amdgcn_s_setprio(0);
      float tm = -3e38f;
      if (k0 >= sq && k0 + 63 < eq) {
#pragma unroll
        for (int j = 0; j < 16; j++) {
          tm = fmaxf(tm, st0[j]);
          tm = fmaxf(tm, st1[j]);
        }
      } else {
#pragma unroll
        for (int j = 0; j < 16; j++) {
          const int crow = (j & 3) + 8 * (j >> 2) + 4 * hi;
          int key0 = k0 + crow, key1 = k0 + 32 + crow;
          st0[j] = (key0 >= sq && key0 < eq) ? st0[j] : -1e30f;
          st1[j] = (key1 >= sq && key1 < eq) ? st1[j] : -1e30f;
          tm = fmaxf(tm, st0[j]);
          tm = fmaxf(tm, st1[j]);
        }
      }
      tm = fmaxf(tm, __shfl_xor(tm, 32));
      if (!__all(tm <= m + 8.f)) {
        const float mn = fmaxf(m, tm);
        const float alpha = __builtin_amdgcn_exp2f(m - mn);
        o0 *= alpha; o1 *= alpha; o2 *= alpha;
        l *= alpha;
        m = mn;
      }
#pragma unroll
      for (int g2 = 0; g2 < 4; g2++) {
#pragma unroll
        for (int hh = 0; hh < 2; hh++) {
          float a0 = __builtin_amdgcn_exp2f(st0[g2 * 4 + 2 * hh] - m);
          float a1 = __builtin_amdgcn_exp2f(st0[g2 * 4 + 2 * hh + 1] - m);
          float b0 = __builtin_amdgcn_exp2f(st1[g2 * 4 + 2 * hh] - m);
          float b1 = __builtin_amdgcn_exp2f(st1[g2 * 4 + 2 * hh + 1] - m);
          rs += a0 + a1 + b0 + b1;
          wd0[g2][hh] = pkbf2(a0, a1);
          wd1[g2][hh] = pkbf2(b0, b1);
        }
      }
      rs += __shfl_xor(rs, 32);
      l += rs;
    }
    asm volatile("s_waitcnt vmcnt(0)" ::: "memory");
    __builtin_amdgcn_s_barrier();
    if (act) {
      __builtin_amdgcn_s_setprio(1);
#pragma unroll
      for (int kk = 0; kk < 4; kk++) {
        const int g2o = (kk & 1) * 2 + hi;
        const int g2s = (kk & 1) * 2 + (hi ^ 1);
        u32 own0, own1, snd0, snd1;
        if (kk < 2) {
          own0 = wd0[g2o][0]; own1 = wd0[g2o][1];
          snd0 = wd0[g2s][0]; snd1 = wd0[g2s][1];
        } else {
          own0 = wd1[g2o][0]; own1 = wd1[g2o][1];
          snd0 = wd1[g2s][0]; snd1 = wd1[g2s][1];
        }
        u32 rc0 = (u32)__shfl_xor((int)snd0, 32);
        u32 rc1 = (u32)__shfl_xor((int)snd1, 32);
        union { u32 w[4]; bf16x8 v; } pf;
        if (hi == 0) { pf.w[0] = own0; pf.w[1] = own1; pf.w[2] = rc0; pf.w[3] = rc1; }
        else         { pf.w[0] = rc0;  pf.w[1] = rc1;  pf.w[2] = own0; pf.w[3] = own1; }
        const int colb = kk * 32 + hi * 16;
#pragma unroll
        for (int mt = 0; mt < 3; mt++) {
          int row = mt * 32 + r31;
          row = row < HD ? row : 0;
          bf16x8 vf = *(const bf16x8*)(Vlp + row * 128 + (colb ^ ((row & 7) << 4)));
          f32x16* op = mt == 0 ? &o0 : (mt == 1 ? &o1 : &o2);
          *op = __builtin_amdgcn_mfma_f32_32x32x16_bf16(vf, pf.v, *op, 0, 0, 0);
        }
      }
      __builtin_amdgcn_s_setprio(0);
    }
  }
  __syncthreads();
  float* mb = (float*)Kl;
  if (pair == 1) {
    float* d = mb + ((size_t)qs * 64 + lane) * 50;
    d[0] = m; d[1] = l;
#pragma unroll
    for (int j = 0; j < 16; j++) { d[2 + j] = o0[j]; d[18 + j] = o1[j]; d[34 + j] = o2[j]; }
  }
  __syncthreads();
  if (pair == 0) {
    const float* d = mb + ((size_t)qs * 64 + lane) * 50;
    const float pm = d[0], pl = d[1];
    const float mn = fmaxf(m, pm);
    const float a = __builtin_amdgcn_exp2f(m - mn);
    const float b = __builtin_amdgcn_exp2f(pm - mn);
    const float lt = l * a + pl * b;
    const float inv = 1.f / lt;
    bf16* orow = Out + (size_t)q * DIM + h * HD;
#pragma unroll
    for (int rg = 0; rg < 4; rg++) {
      bf16x4 v0, v1;
#pragma unroll
      for (int e = 0; e < 4; e++) {
        v0[e] = (bf16)((o0[rg * 4 + e] * a + d[2 + rg * 4 + e] * b) * inv);
        v1[e] = (bf16)((o1[rg * 4 + e] * a + d[18 + rg * 4 + e] * b) * inv);
      }
      *(bf16x4*)(orow + 8 * rg + 4 * hi) = v0;
      *(bf16x4*)(orow + 32 + 8 * rg + 4 * hi) = v1;
    }
#pragma unroll
    for (int rg = 0; rg < 2; rg++) {
      bf16x4 v2;
#pragma unroll
      for (int e = 0; e < 4; e++)
        v2[e] = (bf16)((o2[rg * 4 + e] * a + d[34 + rg * 4 + e] * b) * inv);
      *(bf16x4*)(orow + 64 + 8 * rg + 4 * hi) = v2;
    }
  }
}

// --------------------------- launch -----------------------------------------
extern "C" void kernel_launch(void* const* d_in, const int* in_sizes, int n_in,
                              void* d_out, int out_size, void* d_ws,
                              size_t ws_size, hipStream_t stream) {
  const float* x = (const float*)d_in[0];
  const int* cu = (const int*)d_in[1];
  const float* rope = (const float*)d_in[2];
  const float* w_qkv = (const float*)d_in[3];
  const float* b_qkv = (const float*)d_in[4];
  const float* w_proj = (const float*)d_in[5];
  const float* b_proj = (const float*)d_in[6];
  const int nseg = in_sizes[1] - 1;

  bf16* pA = (bf16*)d_ws;                          // dead after gemm256
  bf16* pB = pA + (size_t)S * DIM;
  bf16* wp16 = pB + (size_t)NQKV * DIM;
  bf16* Qb = wp16 + (size_t)DIM * DIM;             // H*S*80
  bf16* Kb = Qb + (size_t)H * S * HD;              // H*S*128
  bf16* VTb = Kb + (size_t)H * S * KDP;            // H*80*S
  float* ctab = (float*)(VTb + (size_t)H * HD * S);
  float* stab = ctab + (size_t)S * 40;
  bf16* attn16 = pA;                               // alias dead pA

  pack_inputs<<<(int)(TOT_CHUNKS / 256), 256, 0, stream>>>(
      x, w_qkv, w_proj, rope, pA, pB, wp16, Kb, ctab, stab);
  gemm256<<<dim3(NB_B, MB_A), 512, 114688, stream>>>(
      pA, pB, b_qkv, ctab, stab, Qb, Kb, VTb);
  attn_kern<<<H * 48, 256, 0, stream>>>(Qb, Kb, VTb, cu, nseg, attn16);
  gemm_proj<<<dim3(DIM / 128, S / 64), 256, 49152, stream>>>(
      attn16, wp16, b_proj, (float*)d_out, S, DIM, DIM);
}